// Round 13
// baseline (611.315 us; speedup 1.0000x reference)
//
#include <hip/hip_runtime.h>
#include <hip/hip_bf16.h>

#define N_IMG 16
#define C_DIM 512
#define H_DIM 64
#define W_DIM 64
#define HW 4096
#define INTER 512
#define HEADS 64
#define GROUPS 8
#define KSZ 7
#define CPG 64
#define M_TOT (N_IMG * HW)   // 65536 tokens

typedef short bf16x8 __attribute__((ext_vector_type(8)));
typedef short bf16x4 __attribute__((ext_vector_type(4)));
typedef float f32x4 __attribute__((ext_vector_type(4)));
typedef unsigned int u32;

__device__ __forceinline__ unsigned short f2bf(float f) {
    __hip_bfloat16 h = __float2bfloat16(f);
    return *reinterpret_cast<unsigned short*>(&h);
}
__device__ __forceinline__ float bf2f(unsigned short u) {
    u32 x = ((u32)u) << 16;
    union { u32 i; float f; } c; c.i = x; return c.f;
}
__device__ __forceinline__ void gload16(const void* g, void* l) {
    __builtin_amdgcn_global_load_lds(
        (const __attribute__((address_space(1))) u32*)g,
        (__attribute__((address_space(3))) u32*)l, 16, 0, 0);
}
__device__ __forceinline__ void raw_barrier() {
    asm volatile("" ::: "memory");
    __builtin_amdgcn_s_barrier();
    asm volatile("" ::: "memory");
}
#define WAIT_VM(N) asm volatile("s_waitcnt vmcnt(" #N ")" ::: "memory")

// ---------------------------------------------------------------------------
// Kernel P: fused one-time prep. Block ranges select job:
//  [0,6272)      conv weights -> swizzled pk
//  [6272,8320)   k/v proj -> packed staging order
//  [8320,9344)   Pw fp32 -> bf16
//  [9344,9632)   zero crw+esw
//  [9632,18592)  input prepass (padded, swizzled bf16)
// ---------------------------------------------------------------------------
__global__ __launch_bounds__(256) void prep_kernel(
    const float* __restrict__ cw, const float* __restrict__ kw,
    const float* __restrict__ vw, const float* __restrict__ pw,
    const float* __restrict__ x,
    unsigned short* __restrict__ pk, unsigned short* __restrict__ kwb,
    unsigned short* __restrict__ vwb, unsigned short* __restrict__ pwb,
    float* __restrict__ crw, unsigned short* __restrict__ xb)
{
    const int b = blockIdx.x;
    const int tid = threadIdx.x;
    if (b < 6272) {                       // conv weights -> swizzled pk
        int p = b * 256 + tid;            // < 1605632
        int ci = p & 63;
        int co = (p >> 6) & 63;
        int r  = p >> 12;
        int dx = r % 7;
        int dyg = r / 7;
        int dy = dyg % 7;
        int g  = dyg / 7;
        float v = cw[(((size_t)(g * 64 + co)) * 64 + ci) * 49 + dy * 7 + dx];
        pk[(size_t)(g * 49 + dy * 7 + dx) * 4096 + co * 64 + (ci ^ ((co & 7) << 3))] = f2bf(v);
        return;
    }
    if (b < 8320) {                       // k / v proj -> packed staging order
        const float* w = (b < 7296) ? kw : vw;
        unsigned short* wp = (b < 7296) ? kwb : vwb;
        int e = ((b < 7296) ? (b - 6272) : (b - 7296)) * 256 + tid;
        int j = e & 7;
        int chunk = (e >> 3) & 511;
        int kt = (e >> 12) & 15;
        int t = e >> 16;
        int col = chunk & 127, kq = chunk >> 7;
        wp[e] = f2bf(w[(size_t)(t * 128 + col) * 512 + kt * 32 + kq * 8 + j]);
        return;
    }
    if (b < 9344) {                       // Pw fp32 -> bf16 row-major
        int i = (b - 8320) * 256 + tid;
        pwb[i] = f2bf(pw[i]);
        return;
    }
    if (b < 9632) {                       // zero crw+esw (73728 f32)
        crw[(b - 9344) * 256 + tid] = 0.f;
        return;
    }
    // ---- input prepass: 8960 blocks = 16n x 8g x 70row ----
    {
        const int idx = b - 9632;
        const int n   = idx / 560;
        const int rem = idx - n * 560;
        const int g   = rem / 70;
        const int row = rem - g * 70;
        unsigned short* dst = xb + ((size_t)(n * 8 + g) * 70 + row) * 4608;

        if (row < 3 || row > 66) {
            bf16x8 z = (bf16x8){0,0,0,0,0,0,0,0};
            *(bf16x8*)&dst[tid * 8] = z;
            *(bf16x8*)&dst[(256 + tid) * 8] = z;
            if (tid < 64) *(bf16x8*)&dst[(512 + tid) * 8] = z;
            return;
        }
        const int y = row - 3;
        const int xcol = tid & 63;
        const int oct = tid >> 6;
        const int col = xcol + 3;
        const int cswz = (col & 7) << 3;
        const float* src = x + (((size_t)(n * C_DIM + g * CPG)) * H_DIM + y) * W_DIM + xcol;
#pragma unroll
        for (int h = 0; h < 2; ++h) {
            const int ci0 = oct * 16 + h * 8;
            unsigned short tmp[8];
#pragma unroll
            for (int j = 0; j < 8; ++j)
                tmp[j] = f2bf(src[(size_t)(ci0 + j) * (H_DIM * W_DIM)]);
            *(bf16x8*)&dst[col * 64 + (ci0 ^ cswz)] = *(bf16x8*)tmp;
        }
        if (tid < 64) {
            const int hc[8] = {0, 1, 2, 67, 68, 69, 70, 71};
            int c = hc[tid >> 3], o8 = (tid & 7) * 8;
            *(bf16x8*)&dst[c * 64 + (o8 ^ ((c & 7) << 3))] = (bf16x8){0,0,0,0,0,0,0,0};
        }
    }
}

// ---------------------------------------------------------------------------
// Kernel 1: grouped 7x7 conv, 49-tap implicit GEMM, T4 counted-vmcnt
// (R9/R12-proven, unchanged).
// ---------------------------------------------------------------------------
__global__ __launch_bounds__(256) void conv_mfma2_kernel(
    const unsigned short* __restrict__ xb, const unsigned short* __restrict__ pk,
    const float* __restrict__ cb, unsigned short* __restrict__ xc)
{
    __shared__ __align__(16) unsigned short in_ring[4 * 72 * 64];  // 36864 B
    __shared__ __align__(16) unsigned short w_lds[2 * 4096];       // 16384 B

    const int bid  = blockIdx.x;
    const int wgid = (bid & 7) * 256 + (bid >> 3);
    const int g  = wgid >> 8;
    const int n  = (wgid >> 4) & 15;
    const int y0 = (wgid & 15) * 4;
    const int tid  = threadIdx.x;
    const int lane = tid & 63;
    const int wv   = tid >> 6;
    const int lx   = lane & 15;
    const int q4   = lane >> 4;
    const int koff = q4 * 8;
    const int c3   = 512 + (tid & 63);    // uniform 3rd row chunk (dup for tid>=64)

    const unsigned short* xbase = xb + ((size_t)(n * 8 + g) * 70) * 4608;
    const unsigned short* pkg   = pk + (size_t)g * 49 * 4096;

    f32x4 acc[4][4];
#pragma unroll
    for (int i = 0; i < 4; ++i)
#pragma unroll
        for (int j = 0; j < 4; ++j) acc[i][j] = (f32x4){0.f, 0.f, 0.f, 0.f};

    // prologue: rows y0..y0+3 (3 uniform loads each) + tap0 weights (2 loads)
#pragma unroll
    for (int r = 0; r < 4; ++r) {
        const unsigned short* src = xbase + (size_t)(y0 + r) * 4608;
        gload16(src + tid * 8,         &in_ring[r * 4608 + tid * 8]);
        gload16(src + (256 + tid) * 8, &in_ring[r * 4608 + (256 + tid) * 8]);
        gload16(src + c3 * 8,          &in_ring[r * 4608 + c3 * 8]);
    }
    gload16(pkg + tid * 8,         &w_lds[tid * 8]);
    gload16(pkg + (256 + tid) * 8, &w_lds[(256 + tid) * 8]);

    for (int dy = 0; dy < 7; ++dy) {
#pragma unroll
        for (int dx = 0; dx < 7; ++dx) {
            const int t = dy * 7 + dx;
            raw_barrier();                        // retire reads of slots we stage into
            if (dx == 0 && dy > 0) {
                const int slot = (dy + 3) & 3;
                const unsigned short* src = xbase + (size_t)(y0 + dy + 3) * 4608;
                gload16(src + tid * 8,         &in_ring[slot * 4608 + tid * 8]);
                gload16(src + (256 + tid) * 8, &in_ring[slot * 4608 + (256 + tid) * 8]);
                gload16(src + c3 * 8,          &in_ring[slot * 4608 + c3 * 8]);
            }
            if (t < 48) {
                const unsigned short* wsrc = pkg + (size_t)(t + 1) * 4096;
                unsigned short* wdst = &w_lds[((t + 1) & 1) * 4096];
                gload16(wsrc + tid * 8,         wdst + tid * 8);
                gload16(wsrc + (256 + tid) * 8, wdst + (256 + tid) * 8);
                WAIT_VM(2);                       // tap t (+row) done; t+1 in flight
            } else {
                WAIT_VM(0);
            }
            __builtin_amdgcn_sched_barrier(0);
            raw_barrier();                        // all waves' tap-t data visible
            __builtin_amdgcn_sched_barrier(0);

            const unsigned short* wcur = &w_lds[(t & 1) * 4096];
            bf16x8 b[2][4];
#pragma unroll
            for (int kc = 0; kc < 2; ++kc)
#pragma unroll
                for (int ct = 0; ct < 4; ++ct) {
                    const int co = ct * 16 + lx;
                    b[kc][ct] = *(const bf16x8*)
                        &wcur[co * 64 + ((kc * 32 + koff) ^ ((co & 7) << 3))];
                }
            const int col  = wv * 16 + lx + dx;
            const int cswz = (col & 7) << 3;
#pragma unroll
            for (int ty = 0; ty < 4; ++ty) {
                const int slot = (dy + ty) & 3;
#pragma unroll
                for (int kc = 0; kc < 2; ++kc) {
                    bf16x8 a = *(const bf16x8*)
                        &in_ring[slot * 4608 + col * 64 + ((kc * 32 + koff) ^ cswz)];
#pragma unroll
                    for (int ct = 0; ct < 4; ++ct)
                        acc[ty][ct] = __builtin_amdgcn_mfma_f32_16x16x32_bf16(
                            a, b[kc][ct], acc[ty][ct], 0, 0, 0);
                }
            }
        }
    }

#pragma unroll
    for (int ct = 0; ct < 4; ++ct) {
        const float bv = cb[g * 64 + ct * 16 + lx];
        const int cidx = g * 64 + ct * 16 + lx;
#pragma unroll
        for (int ty = 0; ty < 4; ++ty) {
            const int yy = y0 + ty;
#pragma unroll
            for (int r = 0; r < 4; ++r) {
                const int xx = wv * 16 + q4 * 4 + r;
                xc[((size_t)(n * HW + yy * W_DIM + xx)) * INTER + cidx]
                    = f2bf(acc[ty][ct][r] + bv);
            }
        }
    }
}

// ---------------------------------------------------------------------------
// Kernel 2: LayerNorm, one WAVE per row (4 rows/block): bf16x8 loads,
// pure in-wave shuffle reduce — no LDS, no __syncthreads.
// ---------------------------------------------------------------------------
__global__ __launch_bounds__(256) void ln_kernel(
    unsigned short* __restrict__ xc, const float* __restrict__ g,
    const float* __restrict__ b)
{
    const int tid = threadIdx.x;
    const size_t row = (size_t)blockIdx.x * 4 + (tid >> 6);
    const int l = tid & 63;              // 8-elem chunk within row
    unsigned short* p = xc + row * INTER + l * 8;

    bf16x8 u = *(const bf16x8*)p;
    float v[8];
    float s = 0.f, sq = 0.f;
#pragma unroll
    for (int j = 0; j < 8; ++j) {
        v[j] = bf2f((unsigned short)u[j]);
        s += v[j]; sq += v[j] * v[j];
    }
#pragma unroll
    for (int off = 32; off; off >>= 1) {
        s  += __shfl_xor(s, off);
        sq += __shfl_xor(sq, off);
    }
    const float mu  = s * (1.f / INTER);
    const float var = sq * (1.f / INTER) - mu * mu;
    const float rs  = rsqrtf(var + 1e-5f);
    float4 g0 = ((const float4*)g)[l * 2], g1 = ((const float4*)g)[l * 2 + 1];
    float4 b0 = ((const float4*)b)[l * 2], b1 = ((const float4*)b)[l * 2 + 1];
    const float gg[8] = {g0.x, g0.y, g0.z, g0.w, g1.x, g1.y, g1.z, g1.w};
    const float bb[8] = {b0.x, b0.y, b0.z, b0.w, b1.x, b1.y, b1.z, b1.w};
    bf16x8 o;
#pragma unroll
    for (int j = 0; j < 8; ++j)
        o[j] = (short)f2bf((v[j] - mu) * rs * gg[j] + bb[j]);
    *(bf16x8*)p = o;
}

// ---------------------------------------------------------------------------
// Kernel 3a: FUSED k/v GEMM + exp + partial corr, T4 counted-vmcnt.
// R13: LDS 64->48 KB (reduction tiles [128 col][64 tok] x2 = 32 KB, two
// token-half passes, partials in regs, atomics once) + register-lean
// compute phase (only a[4] + streamed bk/bv live) -> target 3 blocks/CU.
// ---------------------------------------------------------------------------
__global__ __launch_bounds__(256) void gemm_kv_corr_kernel(
    const unsigned short* __restrict__ A,
    const unsigned short* __restrict__ Wk, const unsigned short* __restrict__ Wv,
    const float* __restrict__ bk, const float* __restrict__ bv,
    float* __restrict__ crw, float* __restrict__ esw)
{
    __shared__ __align__(16) unsigned short pool[24576];   // 49152 B
    unsigned short* ek_lds = pool;            // [128c][64t] bf16, 16 KB
    unsigned short* v_lds  = pool + 8192;     // [128c][64t] bf16, 16 KB

    const int tid  = threadIdx.x;
    const int lane = tid & 63;
    const int w    = tid >> 6;
    const int lx   = lane & 15;
    const int kq4  = lane >> 4;

    const int orig = blockIdx.x;
    const int wgid = (orig & 7) * 256 + (orig >> 3);   // 2048 = 8*256
    const int m0   = (wgid >> 2) * 128;
    const int ct4  = wgid & 3;
    const int mbase = (w & 1) * 64;
    const int nbase = (w >> 1) * 64;
    const int n = m0 >> 12;

    const unsigned short* wkt = Wk + (size_t)ct4 * 65536;
    const unsigned short* wvt = Wv + (size_t)ct4 * 65536;

    f32x4 acck[4][4], accv[4][4];
#pragma unroll
    for (int i = 0; i < 4; ++i)
#pragma unroll
        for (int j = 0; j < 4; ++j) {
            acck[i][j] = (f32x4){0.f, 0.f, 0.f, 0.f};
            accv[i][j] = (f32x4){0.f, 0.f, 0.f, 0.f};
        }

#pragma unroll
    for (int it = 0; it < 2; ++it) {
        int c = it * 256 + tid;
        gload16(A + (size_t)(m0 + (c & 127)) * 512 + (c >> 7) * 8, &pool[c * 8]);
        gload16(wkt + c * 8, &pool[(1024 + c) * 8]);
        gload16(wvt + c * 8, &pool[(2048 + c) * 8]);
    }

    for (int kt = 0; kt < 16; ++kt) {
        const int b = kt & 1;
        if (kt < 15) {
            const int nb = b ^ 1;
#pragma unroll
            for (int it = 0; it < 2; ++it) {
                int c = it * 256 + tid;
                gload16(A + (size_t)(m0 + (c & 127)) * 512 + (kt + 1) * 32 + (c >> 7) * 8,
                        &pool[(nb * 512 + c) * 8]);
                gload16(wkt + (size_t)(kt + 1) * 4096 + c * 8, &pool[(1024 + nb * 512 + c) * 8]);
                gload16(wvt + (size_t)(kt + 1) * 4096 + c * 8, &pool[(2048 + nb * 512 + c) * 8]);
            }
            WAIT_VM(6);                   // kt's 6 done; kt+1's 6 in flight
        } else {
            WAIT_VM(0);
        }
        __builtin_amdgcn_sched_barrier(0);
        raw_barrier();                    // all waves' kt data visible
        __builtin_amdgcn_sched_barrier(0);

        bf16x8 a[4];
#pragma unroll
        for (int i = 0; i < 4; ++i)
            a[i] = *(const bf16x8*)&pool[(b * 512 + kq4 * 128 + mbase + i * 16 + lx) * 8];
#pragma unroll
        for (int j = 0; j < 4; ++j) {
            bf16x8 bkf = *(const bf16x8*)&pool[(1024 + b * 512 + kq4 * 128 + nbase + j * 16 + lx) * 8];
            bf16x8 bvf = *(const bf16x8*)&pool[(2048 + b * 512 + kq4 * 128 + nbase + j * 16 + lx) * 8];
#pragma unroll
            for (int i = 0; i < 4; ++i) {
                acck[i][j] = __builtin_amdgcn_mfma_f32_16x16x32_bf16(a[i], bkf, acck[i][j], 0, 0, 0);
                accv[i][j] = __builtin_amdgcn_mfma_f32_16x16x32_bf16(a[i], bvf, accv[i][j], 0, 0, 0);
            }
        }
        raw_barrier();                    // retire reads of buf b before next stage
    }

    // ---- two-pass corr reduction (tiles [128 col][64 tok], 32 KB) ----
    const int d = lane >> 3, e = lane & 7;
    float crh[4] = {0.f, 0.f, 0.f, 0.f};
    float esh[4] = {0.f, 0.f, 0.f, 0.f};
#pragma unroll
    for (int p = 0; p < 2; ++p) {
        if (p) raw_barrier();             // pass-0 reads done before overwrite
        if ((w & 1) == p) {               // waves owning token-half p write
#pragma unroll
            for (int j = 0; j < 4; ++j) {
                const int colk = nbase + j * 16 + lx;
                const float bkv = bk[ct4 * 128 + colk];
                const float bvv = bv[ct4 * 128 + colk];
                const int sw = (colk & 7) << 3;
#pragma unroll
                for (int i = 0; i < 4; ++i) {
                    const int t0 = i * 16 + kq4 * 4;     // local 0..63
                    const int idx = colk * 64 + (t0 ^ sw);
                    bf16x4 ew, vw;
#pragma unroll
                    for (int r = 0; r < 4; ++r) {
                        ew[r] = (short)f2bf(__expf(acck[i][j][r] + bkv));
                        vw[r] = (short)f2bf(accv[i][j][r] + bvv);
                    }
                    *(bf16x4*)&ek_lds[idx] = ew;
                    *(bf16x4*)&v_lds[idx]  = vw;
                }
            }
        }
        raw_barrier();                    // tile visible to all waves
#pragma unroll
        for (int h = 0; h < 4; ++h) {
            const int hb = w * 4 + h;     // 4 heads per wave
            const int ck = hb * 8 + d;
            const int ce = hb * 8 + e;
            const int swk = d << 3, swe = e << 3;
#pragma unroll
            for (int tb = 0; tb < 16; ++tb) {
                const int t0 = tb * 4;
                bf16x4 ekv = *(const bf16x4*)&ek_lds[ck * 64 + (t0 ^ swk)];
                bf16x4 vvv = *(const bf16x4*)&v_lds[ce * 64 + (t0 ^ swe)];
#pragma unroll
                for (int r = 0; r < 4; ++r) {
                    float ekf = bf2f((unsigned short)ekv[r]);
                    crh[h] = fmaf(ekf, bf2f((unsigned short)vvv[r]), crh[h]);
                    esh[h] += ekf;
                }
            }
        }
    }
#pragma unroll
    for (int h = 0; h < 4; ++h) {
        const int nh = n * 64 + ct4 * 16 + w * 4 + h;
        atomicAdd(&crw[(size_t)nh * 64 + d * 8 + e], crh[h]);
        if (e == 0) atomicAdd(&esw[nh * 8 + d], esh[h]);
    }
}

// ---------------------------------------------------------------------------
// Kernel 4a: FUSED gcomp + bias2 (independent jobs, block ranges).
// ---------------------------------------------------------------------------
__global__ __launch_bounds__(256) void gcomp_bias2_kernel(
    const float* __restrict__ qw, const float* __restrict__ qb,
    const float* __restrict__ crw, const float* __restrict__ esw,
    const float* __restrict__ pw, const float* __restrict__ pb,
    unsigned short* __restrict__ G, float* __restrict__ b2)
{
    const int blk = blockIdx.x;
    const int tid = threadIdx.x;
    if (blk < 1024) {                     // gcomp
        const int h = blk & 63;
        const int n = blk >> 6;
        const int nh = n * 64 + h;
        __shared__ float C[64];
        if (tid < 64) C[tid] = crw[(size_t)nh * 64 + tid] / esw[nh * 8 + (tid >> 3)];
        __syncthreads();
#pragma unroll
        for (int rep = 0; rep < 2; ++rep) {
            const int k = rep * 256 + tid;
            float o[8] = {};
#pragma unroll
            for (int d = 0; d < 8; ++d) {
                float qv = qw[(size_t)(h * 8 + d) * 512 + k];
#pragma unroll
                for (int e = 0; e < 8; ++e) o[e] = fmaf(qv, C[d * 8 + e], o[e]);
            }
            bf16x8 ov;
#pragma unroll
            for (int e = 0; e < 8; ++e) ov[e] = (short)f2bf(o[e]);
            *(bf16x8*)&G[((size_t)n * 512 + k) * 512 + h * 8] = ov;
        }
        return;
    }
    {                                     // bias2
        const int n = blk - 1024;
        __shared__ float qbc[512];
#pragma unroll
        for (int rep = 0; rep < 2; ++rep) {
            int j = rep * 256 + tid;
            int h = j >> 3, e = j & 7;
            const int nh = n * 64 + h;
            float s = 0.f;
#pragma unroll
            for (int d = 0; d < 8; ++d)
                s += qb[h * 8 + d] * crw[(size_t)nh * 64 + d * 8 + e] / esw[nh * 8 + d];
            qbc[j] = s;
        }
        __syncthreads();
#pragma unroll
        for (int rep = 0; rep < 2; ++rep) {
            int c = rep * 256 + tid;
            const float4* pr = (const float4*)(pw + (size_t)c * 512);
            float s = pb[c];
            for (int q = 0; q < 128; ++q) {
                float4 pv = pr[q];
                s += qbc[q * 4 + 0] * pv.x + qbc[q * 4 + 1] * pv.y
                   + qbc[q * 4 + 2] * pv.z + qbc[q * 4 + 3] * pv.w;
            }
            b2[n * 512 + c] = s;
        }
    }
}

// ---------------------------------------------------------------------------
// Kernel 4b: compose GEMM: Wf_n[c][k] = sum_j Pwb[c][j] * G_n[k][j].
// Epilogue writes DIRECTLY in per-image packed staging order (wfpack fused).
// ---------------------------------------------------------------------------
__global__ __launch_bounds__(256) void compose_kernel(
    const unsigned short* __restrict__ Pwb, const unsigned short* __restrict__ G,
    unsigned short* __restrict__ wfp)
{
    __shared__ __align__(16) unsigned short pool[16384];   // 32768 B
    const int tid  = threadIdx.x;
    const int lane = tid & 63;
    const int w    = tid >> 6;
    const int lx   = lane & 15;
    const int kq4  = lane >> 4;

    const int tile = blockIdx.x;
    const int n    = blockIdx.y;
    const int m0 = (tile >> 2) * 128;    // c-dim
    const int n0 = (tile & 3) * 128;     // k-dim
    const int mbase = (w & 1) * 64;
    const int nbase = (w >> 1) * 64;
    const unsigned short* Gn = G + (size_t)n * 262144;

    f32x4 acc[4][4];
#pragma unroll
    for (int i = 0; i < 4; ++i)
#pragma unroll
        for (int j = 0; j < 4; ++j) acc[i][j] = (f32x4){0.f, 0.f, 0.f, 0.f};

#pragma unroll
    for (int it = 0; it < 2; ++it) {
        int c = it * 256 + tid;
        gload16(Pwb + (size_t)(m0 + (c & 127)) * 512 + (c >> 7) * 8, &pool[c * 8]);
        gload16(Gn + (size_t)(n0 + (c & 127)) * 512 + (c >> 7) * 8, &pool[(1024 + c) * 8]);
    }
    __syncthreads();

    for (int kt = 0; kt < 16; ++kt) {
        const int b = kt & 1;
        if (kt < 15) {
            const int nb = b ^ 1;
#pragma unroll
            for (int it = 0; it < 2; ++it) {
                int c = it * 256 + tid;
                gload16(Pwb + (size_t)(m0 + (c & 127)) * 512 + (kt + 1) * 32 + (c >> 7) * 8,
                        &pool[(nb * 512 + c) * 8]);
                gload16(Gn + (size_t)(n0 + (c & 127)) * 512 + (kt + 1) * 32 + (c >> 7) * 8,
                        &pool[(1024 + nb * 512 + c) * 8]);
            }
        }
        bf16x8 a[4], bf[4];
#pragma unroll
        for (int i = 0; i < 4; ++i) {
            a[i]  = *(const bf16x8*)&pool[(b * 512 + kq4 * 128 + mbase + i * 16 + lx) * 8];
            bf[i] = *(const bf16x8*)&pool[(1024 + b * 512 + kq4 * 128 + nbase + i * 16 + lx) * 8];
        }
#pragma unroll
        for (int i = 0; i < 4; ++i)
#pragma unroll
            for (int j = 0; j < 4; ++j)
                acc[i][j] = __builtin_amdgcn_mfma_f32_16x16x32_bf16(a[i], bf[j], acc[i][j], 0, 0, 0);
        __syncthreads();
    }

    unsigned short* wfn = wfp + (size_t)n * 262144;
#pragma unroll
    for (int j = 0; j < 4; ++j) {
        const int K = n0 + nbase + j * 16 + lx;
        const int kt = K >> 5, kq = (K >> 3) & 3, jp = K & 7;
        const int ebase = (kt << 12) | (kq << 10) | jp;
#pragma unroll
        for (int i = 0; i < 4; ++i) {
            const int rowb = m0 + mbase + i * 16 + kq4 * 4;
#pragma unroll
            for (int r = 0; r < 4; ++r) {
                const int C = rowb + r;
                wfn[((C >> 7) << 16) | ebase | ((C & 127) << 3)] = f2bf(acc[i][j][r]);
            }
        }
    }
}

// ---------------------------------------------------------------------------
// Kernel 5: final composed GEMM, 256x128 tile, T4 counted-vmcnt,
// register-lean compute phase (bf[4] live, A streamed per-i).
// ---------------------------------------------------------------------------
__global__ __launch_bounds__(256) void gemm_p_kernel(
    const unsigned short* __restrict__ A, const unsigned short* __restrict__ Wp,
    const float* __restrict__ bias, float* __restrict__ Y,
    const float* __restrict__ xres, const float* __restrict__ betap)
{
    __shared__ __align__(16) unsigned short pool[24576];   // 49152 B
    const int tid  = threadIdx.x;
    const int lane = tid & 63;
    const int w    = tid >> 6;
    const int lx   = lane & 15;
    const int kq4  = lane >> 4;

    const int orig = blockIdx.x;
    const int wgid = (orig & 7) * 128 + (orig >> 3);       // 1024 = 8*128
    const int m0 = (wgid >> 2) * 256;
    const int n0 = (wgid & 3) * 128;
    const int mbase = (w & 1) * 128;
    const int nbase = (w >> 1) * 64;
    const int nimg = m0 >> 12;

    f32x4 acc[8][4];
#pragma unroll
    for (int i = 0; i < 8; ++i)
#pragma unroll
        for (int j = 0; j < 4; ++j) acc[i][j] = (f32x4){0.f, 0.f, 0.f, 0.f};

    const unsigned short* wpt = Wp + (size_t)nimg * 262144 + (size_t)(wgid & 3) * 65536;

#pragma unroll
    for (int it = 0; it < 4; ++it) {
        int c = it * 256 + tid;
        gload16(A + (size_t)(m0 + (c & 255)) * 512 + (c >> 8) * 8, &pool[c * 8]);
    }
#pragma unroll
    for (int it = 0; it < 2; ++it) {
        int c = it * 256 + tid;
        gload16(wpt + c * 8, &pool[16384 + c * 8]);
    }

    for (int kt = 0; kt < 16; ++kt) {
        const int b = kt & 1;
        if (kt < 15) {
            const int nb = b ^ 1;
#pragma unroll
            for (int it = 0; it < 4; ++it) {
                int c = it * 256 + tid;
                gload16(A + (size_t)(m0 + (c & 255)) * 512 + (kt + 1) * 32 + (c >> 8) * 8,
                        &pool[(nb * 1024 + c) * 8]);
            }
#pragma unroll
            for (int it = 0; it < 2; ++it) {
                int c = it * 256 + tid;
                gload16(wpt + (size_t)(kt + 1) * 4096 + c * 8,
                        &pool[16384 + (nb * 512 + c) * 8]);
            }
            WAIT_VM(6);
        } else {
            WAIT_VM(0);
        }
        __builtin_amdgcn_sched_barrier(0);
        raw_barrier();
        __builtin_amdgcn_sched_barrier(0);

        bf16x8 bf[4];
#pragma unroll
        for (int j = 0; j < 4; ++j)
            bf[j] = *(const bf16x8*)&pool[16384 + (b * 512 + kq4 * 128 + nbase + j * 16 + lx) * 8];
#pragma unroll
        for (int i = 0; i < 8; ++i) {
            bf16x8 ai = *(const bf16x8*)&pool[(b * 1024 + kq4 * 256 + mbase + i * 16 + lx) * 8];
#pragma unroll
            for (int j = 0; j < 4; ++j)
                acc[i][j] = __builtin_amdgcn_mfma_f32_16x16x32_bf16(ai, bf[j], acc[i][j], 0, 0, 0);
        }
        raw_barrier();
    }

    const float beta = betap[0];
#pragma unroll
    for (int j = 0; j < 4; ++j) {
        const int c = n0 + nbase + j * 16 + lx;
        const float pbv = bias[nimg * 512 + c];
        const size_t cbase = ((size_t)(nimg * 512 + c)) * 4096;
#pragma unroll
        for (int i = 0; i < 8; ++i) {
            const int s = (m0 & 4095) + mbase + i * 16 + kq4 * 4;
            float4 xr = *(const float4*)(xres + cbase + s);
            float4 o;
            o.x = beta * (acc[i][j][0] + pbv) + xr.x;
            o.y = beta * (acc[i][j][1] + pbv) + xr.y;
            o.z = beta * (acc[i][j][2] + pbv) + xr.z;
            o.w = beta * (acc[i][j][3] + pbv) + xr.w;
            *(float4*)(Y + cbase + s) = o;
        }
    }
}

// ---------------------------------------------------------------------------
extern "C" void kernel_launch(void* const* d_in, const int* in_sizes, int n_in,
                              void* d_out, int out_size, void* d_ws, size_t ws_size,
                              hipStream_t stream)
{
    (void)in_sizes; (void)n_in; (void)out_size; (void)ws_size;
    const float* x   = (const float*)d_in[0];
    const float* cw  = (const float*)d_in[1];
    const float* cb  = (const float*)d_in[2];
    const float* lng = (const float*)d_in[3];
    const float* lnb = (const float*)d_in[4];
    const float* qw  = (const float*)d_in[5];
    const float* qb  = (const float*)d_in[6];
    const float* kw  = (const float*)d_in[7];
    const float* kb  = (const float*)d_in[8];
    const float* vw  = (const float*)d_in[9];
    const float* vb  = (const float*)d_in[10];
    const float* pw  = (const float*)d_in[11];
    const float* pb  = (const float*)d_in[12];
    const float* beta = (const float*)d_in[13];
    float* out = (float*)d_out;

    char* ws = (char*)d_ws;
    const size_t SZ  = (size_t)M_TOT * INTER * sizeof(float);    // 134 MB
    const size_t HSZ = (size_t)M_TOT * INTER * 2;                // 67 MB
    unsigned short* xc   = (unsigned short*)ws;                  // conv/LN bf16
    unsigned short* G    = (unsigned short*)(ws + HSZ);          // 8 MB
    unsigned short* wfp  = G + (size_t)16 * 262144;              // 8 MB (packed)
    unsigned short* pwb  = wfp + (size_t)16 * 262144;            // 0.5 MB
    float* b2            = (float*)(pwb + 262144);               // 32 KB
    float* crw  = (float*)(ws + SZ);                             // 256 KB partials
    float* esw  = crw + 65536;                                   // 32 KB exp-sums
    unsigned short* pk  = (unsigned short*)(ws + SZ + (2 << 20));  // 3.2 MB
    unsigned short* kwb = (unsigned short*)(ws + SZ + (6 << 20));  // 0.5 MB each
    unsigned short* vwb = kwb + 262144;
    unsigned short* xb  = vwb + 262144;                          // 82.6 MB padded input

    prep_kernel<<<dim3(18592), 256, 0, stream>>>(cw, kw, vw, pw, x,
                                                 pk, kwb, vwb, pwb, crw, xb);

    conv_mfma2_kernel<<<dim3(2048), 256, 0, stream>>>(xb, pk, cb, xc);
    ln_kernel<<<dim3(M_TOT / 4), 256, 0, stream>>>(xc, lng, lnb);

    gemm_kv_corr_kernel<<<dim3(2048), 256, 0, stream>>>(xc, kwb, vwb, kb, vb, crw, esw);

    gcomp_bias2_kernel<<<dim3(1040), 256, 0, stream>>>(qw, qb, crw, esw, pw, pb, G, b2);
    compose_kernel<<<dim3(16, 16), 256, 0, stream>>>(pwb, G, wfp);

    gemm_p_kernel<<<dim3(1024), 256, 0, stream>>>(xc, wfp, b2, out, x, beta);
}

// Round 14
// 489.165 us; speedup vs baseline: 1.2497x; 1.2497x over previous
//
#include <hip/hip_runtime.h>
#include <hip/hip_bf16.h>

#define N_IMG 16
#define C_DIM 512
#define H_DIM 64
#define W_DIM 64
#define HW 4096
#define INTER 512
#define HEADS 64
#define GROUPS 8
#define KSZ 7
#define CPG 64
#define M_TOT (N_IMG * HW)   // 65536 tokens

typedef short bf16x8 __attribute__((ext_vector_type(8)));
typedef short bf16x4 __attribute__((ext_vector_type(4)));
typedef float f32x4 __attribute__((ext_vector_type(4)));
typedef unsigned int u32;

__device__ __forceinline__ unsigned short f2bf(float f) {
    __hip_bfloat16 h = __float2bfloat16(f);
    return *reinterpret_cast<unsigned short*>(&h);
}
__device__ __forceinline__ float bf2f(unsigned short u) {
    u32 x = ((u32)u) << 16;
    union { u32 i; float f; } c; c.i = x; return c.f;
}
__device__ __forceinline__ void gload16(const void* g, void* l) {
    __builtin_amdgcn_global_load_lds(
        (const __attribute__((address_space(1))) u32*)g,
        (__attribute__((address_space(3))) u32*)l, 16, 0, 0);
}
__device__ __forceinline__ void raw_barrier() {
    asm volatile("" ::: "memory");
    __builtin_amdgcn_s_barrier();
    asm volatile("" ::: "memory");
}
#define WAIT_VM(N) asm volatile("s_waitcnt vmcnt(" #N ")" ::: "memory")

// ---------------------------------------------------------------------------
// Kernel P: fused one-time prep. Block ranges select job:
//  [0,6272)      conv weights -> swizzled pk
//  [6272,8320)   k/v proj -> packed staging order
//  [8320,9344)   Pw fp32 -> bf16
//  [9344,9632)   zero crw+esw
//  [9632,18592)  input prepass (padded, swizzled bf16)
// ---------------------------------------------------------------------------
__global__ __launch_bounds__(256) void prep_kernel(
    const float* __restrict__ cw, const float* __restrict__ kw,
    const float* __restrict__ vw, const float* __restrict__ pw,
    const float* __restrict__ x,
    unsigned short* __restrict__ pk, unsigned short* __restrict__ kwb,
    unsigned short* __restrict__ vwb, unsigned short* __restrict__ pwb,
    float* __restrict__ crw, unsigned short* __restrict__ xb)
{
    const int b = blockIdx.x;
    const int tid = threadIdx.x;
    if (b < 6272) {                       // conv weights -> swizzled pk
        int p = b * 256 + tid;            // < 1605632
        int ci = p & 63;
        int co = (p >> 6) & 63;
        int r  = p >> 12;
        int dx = r % 7;
        int dyg = r / 7;
        int dy = dyg % 7;
        int g  = dyg / 7;
        float v = cw[(((size_t)(g * 64 + co)) * 64 + ci) * 49 + dy * 7 + dx];
        pk[(size_t)(g * 49 + dy * 7 + dx) * 4096 + co * 64 + (ci ^ ((co & 7) << 3))] = f2bf(v);
        return;
    }
    if (b < 8320) {                       // k / v proj -> packed staging order
        const float* w = (b < 7296) ? kw : vw;
        unsigned short* wp = (b < 7296) ? kwb : vwb;
        int e = ((b < 7296) ? (b - 6272) : (b - 7296)) * 256 + tid;
        int j = e & 7;
        int chunk = (e >> 3) & 511;
        int kt = (e >> 12) & 15;
        int t = e >> 16;
        int col = chunk & 127, kq = chunk >> 7;
        wp[e] = f2bf(w[(size_t)(t * 128 + col) * 512 + kt * 32 + kq * 8 + j]);
        return;
    }
    if (b < 9344) {                       // Pw fp32 -> bf16 row-major
        int i = (b - 8320) * 256 + tid;
        pwb[i] = f2bf(pw[i]);
        return;
    }
    if (b < 9632) {                       // zero crw+esw (73728 f32)
        crw[(b - 9344) * 256 + tid] = 0.f;
        return;
    }
    // ---- input prepass: 8960 blocks = 16n x 8g x 70row ----
    {
        const int idx = b - 9632;
        const int n   = idx / 560;
        const int rem = idx - n * 560;
        const int g   = rem / 70;
        const int row = rem - g * 70;
        unsigned short* dst = xb + ((size_t)(n * 8 + g) * 70 + row) * 4608;

        if (row < 3 || row > 66) {
            bf16x8 z = (bf16x8){0,0,0,0,0,0,0,0};
            *(bf16x8*)&dst[tid * 8] = z;
            *(bf16x8*)&dst[(256 + tid) * 8] = z;
            if (tid < 64) *(bf16x8*)&dst[(512 + tid) * 8] = z;
            return;
        }
        const int y = row - 3;
        const int xcol = tid & 63;
        const int oct = tid >> 6;
        const int col = xcol + 3;
        const int cswz = (col & 7) << 3;
        const float* src = x + (((size_t)(n * C_DIM + g * CPG)) * H_DIM + y) * W_DIM + xcol;
#pragma unroll
        for (int h = 0; h < 2; ++h) {
            const int ci0 = oct * 16 + h * 8;
            unsigned short tmp[8];
#pragma unroll
            for (int j = 0; j < 8; ++j)
                tmp[j] = f2bf(src[(size_t)(ci0 + j) * (H_DIM * W_DIM)]);
            *(bf16x8*)&dst[col * 64 + (ci0 ^ cswz)] = *(bf16x8*)tmp;
        }
        if (tid < 64) {
            const int hc[8] = {0, 1, 2, 67, 68, 69, 70, 71};
            int c = hc[tid >> 3], o8 = (tid & 7) * 8;
            *(bf16x8*)&dst[c * 64 + (o8 ^ ((c & 7) << 3))] = (bf16x8){0,0,0,0,0,0,0,0};
        }
    }
}

// ---------------------------------------------------------------------------
// Kernel 1: grouped 7x7 conv, 49-tap implicit GEMM, T4 counted-vmcnt
// (R9/R12-proven, unchanged).
// ---------------------------------------------------------------------------
__global__ __launch_bounds__(256) void conv_mfma2_kernel(
    const unsigned short* __restrict__ xb, const unsigned short* __restrict__ pk,
    const float* __restrict__ cb, unsigned short* __restrict__ xc)
{
    __shared__ __align__(16) unsigned short in_ring[4 * 72 * 64];  // 36864 B
    __shared__ __align__(16) unsigned short w_lds[2 * 4096];       // 16384 B

    const int bid  = blockIdx.x;
    const int wgid = (bid & 7) * 256 + (bid >> 3);
    const int g  = wgid >> 8;
    const int n  = (wgid >> 4) & 15;
    const int y0 = (wgid & 15) * 4;
    const int tid  = threadIdx.x;
    const int lane = tid & 63;
    const int wv   = tid >> 6;
    const int lx   = lane & 15;
    const int q4   = lane >> 4;
    const int koff = q4 * 8;
    const int c3   = 512 + (tid & 63);    // uniform 3rd row chunk (dup for tid>=64)

    const unsigned short* xbase = xb + ((size_t)(n * 8 + g) * 70) * 4608;
    const unsigned short* pkg   = pk + (size_t)g * 49 * 4096;

    f32x4 acc[4][4];
#pragma unroll
    for (int i = 0; i < 4; ++i)
#pragma unroll
        for (int j = 0; j < 4; ++j) acc[i][j] = (f32x4){0.f, 0.f, 0.f, 0.f};

    // prologue: rows y0..y0+3 (3 uniform loads each) + tap0 weights (2 loads)
#pragma unroll
    for (int r = 0; r < 4; ++r) {
        const unsigned short* src = xbase + (size_t)(y0 + r) * 4608;
        gload16(src + tid * 8,         &in_ring[r * 4608 + tid * 8]);
        gload16(src + (256 + tid) * 8, &in_ring[r * 4608 + (256 + tid) * 8]);
        gload16(src + c3 * 8,          &in_ring[r * 4608 + c3 * 8]);
    }
    gload16(pkg + tid * 8,         &w_lds[tid * 8]);
    gload16(pkg + (256 + tid) * 8, &w_lds[(256 + tid) * 8]);

    for (int dy = 0; dy < 7; ++dy) {
#pragma unroll
        for (int dx = 0; dx < 7; ++dx) {
            const int t = dy * 7 + dx;
            raw_barrier();                        // retire reads of slots we stage into
            if (dx == 0 && dy > 0) {
                const int slot = (dy + 3) & 3;
                const unsigned short* src = xbase + (size_t)(y0 + dy + 3) * 4608;
                gload16(src + tid * 8,         &in_ring[slot * 4608 + tid * 8]);
                gload16(src + (256 + tid) * 8, &in_ring[slot * 4608 + (256 + tid) * 8]);
                gload16(src + c3 * 8,          &in_ring[slot * 4608 + c3 * 8]);
            }
            if (t < 48) {
                const unsigned short* wsrc = pkg + (size_t)(t + 1) * 4096;
                unsigned short* wdst = &w_lds[((t + 1) & 1) * 4096];
                gload16(wsrc + tid * 8,         wdst + tid * 8);
                gload16(wsrc + (256 + tid) * 8, wdst + (256 + tid) * 8);
                WAIT_VM(2);                       // tap t (+row) done; t+1 in flight
            } else {
                WAIT_VM(0);
            }
            __builtin_amdgcn_sched_barrier(0);
            raw_barrier();                        // all waves' tap-t data visible
            __builtin_amdgcn_sched_barrier(0);

            const unsigned short* wcur = &w_lds[(t & 1) * 4096];
            bf16x8 b[2][4];
#pragma unroll
            for (int kc = 0; kc < 2; ++kc)
#pragma unroll
                for (int ct = 0; ct < 4; ++ct) {
                    const int co = ct * 16 + lx;
                    b[kc][ct] = *(const bf16x8*)
                        &wcur[co * 64 + ((kc * 32 + koff) ^ ((co & 7) << 3))];
                }
            const int col  = wv * 16 + lx + dx;
            const int cswz = (col & 7) << 3;
#pragma unroll
            for (int ty = 0; ty < 4; ++ty) {
                const int slot = (dy + ty) & 3;
#pragma unroll
                for (int kc = 0; kc < 2; ++kc) {
                    bf16x8 a = *(const bf16x8*)
                        &in_ring[slot * 4608 + col * 64 + ((kc * 32 + koff) ^ cswz)];
#pragma unroll
                    for (int ct = 0; ct < 4; ++ct)
                        acc[ty][ct] = __builtin_amdgcn_mfma_f32_16x16x32_bf16(
                            a, b[kc][ct], acc[ty][ct], 0, 0, 0);
                }
            }
        }
    }

#pragma unroll
    for (int ct = 0; ct < 4; ++ct) {
        const float bv = cb[g * 64 + ct * 16 + lx];
        const int cidx = g * 64 + ct * 16 + lx;
#pragma unroll
        for (int ty = 0; ty < 4; ++ty) {
            const int yy = y0 + ty;
#pragma unroll
            for (int r = 0; r < 4; ++r) {
                const int xx = wv * 16 + q4 * 4 + r;
                xc[((size_t)(n * HW + yy * W_DIM + xx)) * INTER + cidx]
                    = f2bf(acc[ty][ct][r] + bv);
            }
        }
    }
}

// ---------------------------------------------------------------------------
// Kernel 2: LayerNorm, one WAVE per row (4 rows/block): bf16x8 loads,
// pure in-wave shuffle reduce — no LDS, no __syncthreads.
// ---------------------------------------------------------------------------
__global__ __launch_bounds__(256) void ln_kernel(
    unsigned short* __restrict__ xc, const float* __restrict__ g,
    const float* __restrict__ b)
{
    const int tid = threadIdx.x;
    const size_t row = (size_t)blockIdx.x * 4 + (tid >> 6);
    const int l = tid & 63;              // 8-elem chunk within row
    unsigned short* p = xc + row * INTER + l * 8;

    bf16x8 u = *(const bf16x8*)p;
    float v[8];
    float s = 0.f, sq = 0.f;
#pragma unroll
    for (int j = 0; j < 8; ++j) {
        v[j] = bf2f((unsigned short)u[j]);
        s += v[j]; sq += v[j] * v[j];
    }
#pragma unroll
    for (int off = 32; off; off >>= 1) {
        s  += __shfl_xor(s, off);
        sq += __shfl_xor(sq, off);
    }
    const float mu  = s * (1.f / INTER);
    const float var = sq * (1.f / INTER) - mu * mu;
    const float rs  = rsqrtf(var + 1e-5f);
    float4 g0 = ((const float4*)g)[l * 2], g1 = ((const float4*)g)[l * 2 + 1];
    float4 b0 = ((const float4*)b)[l * 2], b1 = ((const float4*)b)[l * 2 + 1];
    const float gg[8] = {g0.x, g0.y, g0.z, g0.w, g1.x, g1.y, g1.z, g1.w};
    const float bb[8] = {b0.x, b0.y, b0.z, b0.w, b1.x, b1.y, b1.z, b1.w};
    bf16x8 o;
#pragma unroll
    for (int j = 0; j < 8; ++j)
        o[j] = (short)f2bf((v[j] - mu) * rs * gg[j] + bb[j]);
    *(bf16x8*)p = o;
}

// ---------------------------------------------------------------------------
// Kernel 3a: FUSED k/v GEMM + exp + partial corr, T4 counted-vmcnt
// (R12-proven version, fully restored).
// ---------------------------------------------------------------------------
__global__ __launch_bounds__(256, 2) void gemm_kv_corr_kernel(
    const unsigned short* __restrict__ A,
    const unsigned short* __restrict__ Wk, const unsigned short* __restrict__ Wv,
    const float* __restrict__ bk, const float* __restrict__ bv,
    float* __restrict__ crw, float* __restrict__ esw)
{
    __shared__ __align__(16) unsigned short pool[32768];   // 65536 B
    unsigned short* ek_lds = pool;
    unsigned short* v_lds  = pool + 16384;

    const int tid  = threadIdx.x;
    const int lane = tid & 63;
    const int w    = tid >> 6;
    const int lx   = lane & 15;
    const int kq4  = lane >> 4;

    const int orig = blockIdx.x;
    const int wgid = (orig & 7) * 256 + (orig >> 3);   // 2048 = 8*256
    const int m0   = (wgid >> 2) * 128;
    const int ct4  = wgid & 3;
    const int mbase = (w & 1) * 64;
    const int nbase = (w >> 1) * 64;
    const int n = m0 >> 12;

    const unsigned short* wkt = Wk + (size_t)ct4 * 65536;
    const unsigned short* wvt = Wv + (size_t)ct4 * 65536;

    f32x4 acck[4][4], accv[4][4];
#pragma unroll
    for (int i = 0; i < 4; ++i)
#pragma unroll
        for (int j = 0; j < 4; ++j) {
            acck[i][j] = (f32x4){0.f, 0.f, 0.f, 0.f};
            accv[i][j] = (f32x4){0.f, 0.f, 0.f, 0.f};
        }

#pragma unroll
    for (int it = 0; it < 2; ++it) {
        int c = it * 256 + tid;
        gload16(A + (size_t)(m0 + (c & 127)) * 512 + (c >> 7) * 8, &pool[c * 8]);
        gload16(wkt + c * 8, &pool[(1024 + c) * 8]);
        gload16(wvt + c * 8, &pool[(2048 + c) * 8]);
    }

    for (int kt = 0; kt < 16; ++kt) {
        const int b = kt & 1;
        if (kt < 15) {
            const int nb = b ^ 1;
#pragma unroll
            for (int it = 0; it < 2; ++it) {
                int c = it * 256 + tid;
                gload16(A + (size_t)(m0 + (c & 127)) * 512 + (kt + 1) * 32 + (c >> 7) * 8,
                        &pool[(nb * 512 + c) * 8]);
                gload16(wkt + (size_t)(kt + 1) * 4096 + c * 8, &pool[(1024 + nb * 512 + c) * 8]);
                gload16(wvt + (size_t)(kt + 1) * 4096 + c * 8, &pool[(2048 + nb * 512 + c) * 8]);
            }
            WAIT_VM(6);                   // kt's 6 done; kt+1's 6 in flight
        } else {
            WAIT_VM(0);
        }
        __builtin_amdgcn_sched_barrier(0);
        raw_barrier();                    // all waves' kt data visible
        __builtin_amdgcn_sched_barrier(0);

        bf16x8 a[4], bkf[4], bvf[4];
#pragma unroll
        for (int i = 0; i < 4; ++i) {
            a[i]   = *(const bf16x8*)&pool[(b * 512 + kq4 * 128 + mbase + i * 16 + lx) * 8];
            bkf[i] = *(const bf16x8*)&pool[(1024 + b * 512 + kq4 * 128 + nbase + i * 16 + lx) * 8];
            bvf[i] = *(const bf16x8*)&pool[(2048 + b * 512 + kq4 * 128 + nbase + i * 16 + lx) * 8];
        }
#pragma unroll
        for (int i = 0; i < 4; ++i)
#pragma unroll
            for (int j = 0; j < 4; ++j) {
                acck[i][j] = __builtin_amdgcn_mfma_f32_16x16x32_bf16(a[i], bkf[j], acck[i][j], 0, 0, 0);
                accv[i][j] = __builtin_amdgcn_mfma_f32_16x16x32_bf16(a[i], bvf[j], accv[i][j], 0, 0, 0);
            }
        raw_barrier();                    // retire reads of buf b before next stage
    }

    // stage exp(k+bk), v+bv into transposed swizzled bf16 tiles
#pragma unroll
    for (int j = 0; j < 4; ++j) {
        const int colk = nbase + j * 16 + lx;
        const float bkv = bk[ct4 * 128 + colk];
        const float bvv = bv[ct4 * 128 + colk];
        const int sw = (colk & 7) << 3;
#pragma unroll
        for (int i = 0; i < 4; ++i) {
            const int t0 = mbase + i * 16 + kq4 * 4;
            const int idx = colk * 128 + (t0 ^ sw);
            bf16x4 ew, vw;
#pragma unroll
            for (int r = 0; r < 4; ++r) {
                ew[r] = (short)f2bf(__expf(acck[i][j][r] + bkv));
                vw[r] = (short)f2bf(accv[i][j][r] + bvv);
            }
            *(bf16x4*)&ek_lds[idx] = ew;
            *(bf16x4*)&v_lds[idx]  = vw;
        }
    }
    const int d = lane >> 3, e = lane & 7;
    const int hbase = (w >> 1) * 8;
#pragma unroll
    for (int h = 0; h < 8; ++h) {
        const int hb = hbase + h;
        const int ck = hb * 8 + d;
        const int ce = hb * 8 + e;
        const int swk = d << 3, swe = e << 3;
        float crh = 0.f, esh = 0.f;
#pragma unroll
        for (int tb = 0; tb < 16; ++tb) {
            const int t0 = mbase + tb * 4;
            bf16x4 ekv = *(const bf16x4*)&ek_lds[ck * 128 + (t0 ^ swk)];
            bf16x4 vvv = *(const bf16x4*)&v_lds[ce * 128 + (t0 ^ swe)];
#pragma unroll
            for (int r = 0; r < 4; ++r) {
                float ekf = bf2f((unsigned short)ekv[r]);
                crh = fmaf(ekf, bf2f((unsigned short)vvv[r]), crh);
                esh += ekf;
            }
        }
        const int nh = n * 64 + ct4 * 16 + hb;
        atomicAdd(&crw[(size_t)nh * 64 + d * 8 + e], crh);
        if (e == 0) atomicAdd(&esw[nh * 8 + d], esh);
    }
}

// ---------------------------------------------------------------------------
// Kernel 4a: FUSED gcomp + bias2 (independent jobs, block ranges).
//  [0,1024):   G_n[k][j] = (Qw^T . C_n)[k][j], normalization fused
//  [1024,1040): b2_n[c] = sum_j (qb.C_n)[j]*Pw[c][j] + pb[c]
// ---------------------------------------------------------------------------
__global__ __launch_bounds__(256) void gcomp_bias2_kernel(
    const float* __restrict__ qw, const float* __restrict__ qb,
    const float* __restrict__ crw, const float* __restrict__ esw,
    const float* __restrict__ pw, const float* __restrict__ pb,
    unsigned short* __restrict__ G, float* __restrict__ b2)
{
    const int blk = blockIdx.x;
    const int tid = threadIdx.x;
    if (blk < 1024) {                     // gcomp
        const int h = blk & 63;
        const int n = blk >> 6;
        const int nh = n * 64 + h;
        __shared__ float C[64];
        if (tid < 64) C[tid] = crw[(size_t)nh * 64 + tid] / esw[nh * 8 + (tid >> 3)];
        __syncthreads();
#pragma unroll
        for (int rep = 0; rep < 2; ++rep) {
            const int k = rep * 256 + tid;
            float o[8] = {};
#pragma unroll
            for (int d = 0; d < 8; ++d) {
                float qv = qw[(size_t)(h * 8 + d) * 512 + k];
#pragma unroll
                for (int e = 0; e < 8; ++e) o[e] = fmaf(qv, C[d * 8 + e], o[e]);
            }
            bf16x8 ov;
#pragma unroll
            for (int e = 0; e < 8; ++e) ov[e] = (short)f2bf(o[e]);
            *(bf16x8*)&G[((size_t)n * 512 + k) * 512 + h * 8] = ov;
        }
        return;
    }
    {                                     // bias2
        const int n = blk - 1024;
        __shared__ float qbc[512];
#pragma unroll
        for (int rep = 0; rep < 2; ++rep) {
            int j = rep * 256 + tid;
            int h = j >> 3, e = j & 7;
            const int nh = n * 64 + h;
            float s = 0.f;
#pragma unroll
            for (int d = 0; d < 8; ++d)
                s += qb[h * 8 + d] * crw[(size_t)nh * 64 + d * 8 + e] / esw[nh * 8 + d];
            qbc[j] = s;
        }
        __syncthreads();
#pragma unroll
        for (int rep = 0; rep < 2; ++rep) {
            int c = rep * 256 + tid;
            const float4* pr = (const float4*)(pw + (size_t)c * 512);
            float s = pb[c];
            for (int q = 0; q < 128; ++q) {
                float4 pv = pr[q];
                s += qbc[q * 4 + 0] * pv.x + qbc[q * 4 + 1] * pv.y
                   + qbc[q * 4 + 2] * pv.z + qbc[q * 4 + 3] * pv.w;
            }
            b2[n * 512 + c] = s;
        }
    }
}

// ---------------------------------------------------------------------------
// Kernel 4b: compose GEMM: Wf_n[c][k] = sum_j Pwb[c][j] * G_n[k][j].
// Epilogue writes DIRECTLY in per-image packed staging order (wfpack fused).
// ---------------------------------------------------------------------------
__global__ __launch_bounds__(256) void compose_kernel(
    const unsigned short* __restrict__ Pwb, const unsigned short* __restrict__ G,
    unsigned short* __restrict__ wfp)
{
    __shared__ __align__(16) unsigned short pool[16384];   // 32768 B
    const int tid  = threadIdx.x;
    const int lane = tid & 63;
    const int w    = tid >> 6;
    const int lx   = lane & 15;
    const int kq4  = lane >> 4;

    const int tile = blockIdx.x;
    const int n    = blockIdx.y;
    const int m0 = (tile >> 2) * 128;    // c-dim
    const int n0 = (tile & 3) * 128;     // k-dim
    const int mbase = (w & 1) * 64;
    const int nbase = (w >> 1) * 64;
    const unsigned short* Gn = G + (size_t)n * 262144;

    f32x4 acc[4][4];
#pragma unroll
    for (int i = 0; i < 4; ++i)
#pragma unroll
        for (int j = 0; j < 4; ++j) acc[i][j] = (f32x4){0.f, 0.f, 0.f, 0.f};

#pragma unroll
    for (int it = 0; it < 2; ++it) {
        int c = it * 256 + tid;
        gload16(Pwb + (size_t)(m0 + (c & 127)) * 512 + (c >> 7) * 8, &pool[c * 8]);
        gload16(Gn + (size_t)(n0 + (c & 127)) * 512 + (c >> 7) * 8, &pool[(1024 + c) * 8]);
    }
    __syncthreads();

    for (int kt = 0; kt < 16; ++kt) {
        const int b = kt & 1;
        if (kt < 15) {
            const int nb = b ^ 1;
#pragma unroll
            for (int it = 0; it < 2; ++it) {
                int c = it * 256 + tid;
                gload16(Pwb + (size_t)(m0 + (c & 127)) * 512 + (kt + 1) * 32 + (c >> 7) * 8,
                        &pool[(nb * 512 + c) * 8]);
                gload16(Gn + (size_t)(n0 + (c & 127)) * 512 + (kt + 1) * 32 + (c >> 7) * 8,
                        &pool[(1024 + nb * 512 + c) * 8]);
            }
        }
        bf16x8 a[4], bf[4];
#pragma unroll
        for (int i = 0; i < 4; ++i) {
            a[i]  = *(const bf16x8*)&pool[(b * 512 + kq4 * 128 + mbase + i * 16 + lx) * 8];
            bf[i] = *(const bf16x8*)&pool[(1024 + b * 512 + kq4 * 128 + nbase + i * 16 + lx) * 8];
        }
#pragma unroll
        for (int i = 0; i < 4; ++i)
#pragma unroll
            for (int j = 0; j < 4; ++j)
                acc[i][j] = __builtin_amdgcn_mfma_f32_16x16x32_bf16(a[i], bf[j], acc[i][j], 0, 0, 0);
        __syncthreads();
    }

    unsigned short* wfn = wfp + (size_t)n * 262144;
#pragma unroll
    for (int j = 0; j < 4; ++j) {
        const int K = n0 + nbase + j * 16 + lx;
        const int kt = K >> 5, kq = (K >> 3) & 3, jp = K & 7;
        const int ebase = (kt << 12) | (kq << 10) | jp;
#pragma unroll
        for (int i = 0; i < 4; ++i) {
            const int rowb = m0 + mbase + i * 16 + kq4 * 4;
#pragma unroll
            for (int r = 0; r < 4; ++r) {
                const int C = rowb + r;
                wfn[((C >> 7) << 16) | ebase | ((C & 127) << 3)] = f2bf(acc[i][j][r]);
            }
        }
    }
}

// ---------------------------------------------------------------------------
// Kernel 5: final composed GEMM, 256x128 tile, T4 counted-vmcnt (R12),
// per-image weights/bias, fused epilogue beta*(y+b2)+x, store out[n][c][s].
// ---------------------------------------------------------------------------
__global__ __launch_bounds__(256) void gemm_p_kernel(
    const unsigned short* __restrict__ A, const unsigned short* __restrict__ Wp,
    const float* __restrict__ bias, float* __restrict__ Y,
    const float* __restrict__ xres, const float* __restrict__ betap)
{
    __shared__ __align__(16) unsigned short pool[24576];   // 49152 B
    const int tid  = threadIdx.x;
    const int lane = tid & 63;
    const int w    = tid >> 6;
    const int lx   = lane & 15;
    const int kq4  = lane >> 4;

    const int orig = blockIdx.x;
    const int wgid = (orig & 7) * 128 + (orig >> 3);       // 1024 = 8*128
    const int m0 = (wgid >> 2) * 256;
    const int n0 = (wgid & 3) * 128;
    const int mbase = (w & 1) * 128;
    const int nbase = (w >> 1) * 64;
    const int nimg = m0 >> 12;

    f32x4 acc[8][4];
#pragma unroll
    for (int i = 0; i < 8; ++i)
#pragma unroll
        for (int j = 0; j < 4; ++j) acc[i][j] = (f32x4){0.f, 0.f, 0.f, 0.f};

    const unsigned short* wpt = Wp + (size_t)nimg * 262144 + (size_t)(wgid & 3) * 65536;

#pragma unroll
    for (int it = 0; it < 4; ++it) {
        int c = it * 256 + tid;
        gload16(A + (size_t)(m0 + (c & 255)) * 512 + (c >> 8) * 8, &pool[c * 8]);
    }
#pragma unroll
    for (int it = 0; it < 2; ++it) {
        int c = it * 256 + tid;
        gload16(wpt + c * 8, &pool[16384 + c * 8]);
    }

    for (int kt = 0; kt < 16; ++kt) {
        const int b = kt & 1;
        if (kt < 15) {
            const int nb = b ^ 1;
#pragma unroll
            for (int it = 0; it < 4; ++it) {
                int c = it * 256 + tid;
                gload16(A + (size_t)(m0 + (c & 255)) * 512 + (kt + 1) * 32 + (c >> 8) * 8,
                        &pool[(nb * 1024 + c) * 8]);
            }
#pragma unroll
            for (int it = 0; it < 2; ++it) {
                int c = it * 256 + tid;
                gload16(wpt + (size_t)(kt + 1) * 4096 + c * 8,
                        &pool[16384 + (nb * 512 + c) * 8]);
            }
            WAIT_VM(6);
        } else {
            WAIT_VM(0);
        }
        __builtin_amdgcn_sched_barrier(0);
        raw_barrier();
        __builtin_amdgcn_sched_barrier(0);

        bf16x8 a[8], bf[4];
#pragma unroll
        for (int i = 0; i < 8; ++i)
            a[i] = *(const bf16x8*)&pool[(b * 1024 + kq4 * 256 + mbase + i * 16 + lx) * 8];
#pragma unroll
        for (int j = 0; j < 4; ++j)
            bf[j] = *(const bf16x8*)&pool[16384 + (b * 512 + kq4 * 128 + nbase + j * 16 + lx) * 8];
#pragma unroll
        for (int i = 0; i < 8; ++i)
#pragma unroll
            for (int j = 0; j < 4; ++j)
                acc[i][j] = __builtin_amdgcn_mfma_f32_16x16x32_bf16(a[i], bf[j], acc[i][j], 0, 0, 0);
        raw_barrier();
    }

    const float beta = betap[0];
#pragma unroll
    for (int j = 0; j < 4; ++j) {
        const int c = n0 + nbase + j * 16 + lx;
        const float pbv = bias[nimg * 512 + c];
        const size_t cbase = ((size_t)(nimg * 512 + c)) * 4096;
#pragma unroll
        for (int i = 0; i < 8; ++i) {
            const int s = (m0 & 4095) + mbase + i * 16 + kq4 * 4;
            float4 xr = *(const float4*)(xres + cbase + s);
            float4 o;
            o.x = beta * (acc[i][j][0] + pbv) + xr.x;
            o.y = beta * (acc[i][j][1] + pbv) + xr.y;
            o.z = beta * (acc[i][j][2] + pbv) + xr.z;
            o.w = beta * (acc[i][j][3] + pbv) + xr.w;
            *(float4*)(Y + cbase + s) = o;
        }
    }
}

// ---------------------------------------------------------------------------
extern "C" void kernel_launch(void* const* d_in, const int* in_sizes, int n_in,
                              void* d_out, int out_size, void* d_ws, size_t ws_size,
                              hipStream_t stream)
{
    (void)in_sizes; (void)n_in; (void)out_size; (void)ws_size;
    const float* x   = (const float*)d_in[0];
    const float* cw  = (const float*)d_in[1];
    const float* cb  = (const float*)d_in[2];
    const float* lng = (const float*)d_in[3];
    const float* lnb = (const float*)d_in[4];
    const float* qw  = (const float*)d_in[5];
    const float* qb  = (const float*)d_in[6];
    const float* kw  = (const float*)d_in[7];
    const float* kb  = (const float*)d_in[8];
    const float* vw  = (const float*)d_in[9];
    const float* vb  = (const float*)d_in[10];
    const float* pw  = (const float*)d_in[11];
    const float* pb  = (const float*)d_in[12];
    const float* beta = (const float*)d_in[13];
    float* out = (float*)d_out;

    char* ws = (char*)d_ws;
    const size_t SZ  = (size_t)M_TOT * INTER * sizeof(float);    // 134 MB
    const size_t HSZ = (size_t)M_TOT * INTER * 2;                // 67 MB
    unsigned short* xc   = (unsigned short*)ws;                  // conv/LN bf16
    unsigned short* G    = (unsigned short*)(ws + HSZ);          // 8 MB
    unsigned short* wfp  = G + (size_t)16 * 262144;              // 8 MB (packed)
    unsigned short* pwb  = wfp + (size_t)16 * 262144;            // 0.5 MB
    float* b2            = (float*)(pwb + 262144);               // 32 KB
    float* crw  = (float*)(ws + SZ);                             // 256 KB partials
    float* esw  = crw + 65536;                                   // 32 KB exp-sums
    unsigned short* pk  = (unsigned short*)(ws + SZ + (2 << 20));  // 3.2 MB
    unsigned short* kwb = (unsigned short*)(ws + SZ + (6 << 20));  // 0.5 MB each
    unsigned short* vwb = kwb + 262144;
    unsigned short* xb  = vwb + 262144;                          // 82.6 MB padded input

    prep_kernel<<<dim3(18592), 256, 0, stream>>>(cw, kw, vw, pw, x,
                                                 pk, kwb, vwb, pwb, crw, xb);

    conv_mfma2_kernel<<<dim3(2048), 256, 0, stream>>>(xb, pk, cb, xc);
    ln_kernel<<<dim3(M_TOT / 4), 256, 0, stream>>>(xc, lng, lnb);

    gemm_kv_corr_kernel<<<dim3(2048), 256, 0, stream>>>(xc, kwb, vwb, kb, vb, crw, esw);

    gcomp_bias2_kernel<<<dim3(1040), 256, 0, stream>>>(qw, qb, crw, esw, pw, pb, G, b2);
    compose_kernel<<<dim3(16, 16), 256, 0, stream>>>(pwb, G, wfp);

    gemm_p_kernel<<<dim3(1024), 256, 0, stream>>>(xc, wfp, b2, out, x, beta);
}